// Round 2
// baseline (671.536 us; speedup 1.0000x reference)
//
#include <hip/hip_runtime.h>
#include <hip/hip_bf16.h>

#define N_NODES 100000
#define N_EDGES 1600000

__device__ __forceinline__ float rlane(float v, int l) {
  return __uint_as_float(__builtin_amdgcn_readlane(__float_as_uint(v), l));
}

// ---- CSR build -------------------------------------------------------------

__global__ void k_hist(const int* __restrict__ dst, int* __restrict__ deg) {
  int stride = gridDim.x * blockDim.x;
  for (int e = blockIdx.x * blockDim.x + threadIdx.x; e < N_EDGES; e += stride)
    atomicAdd(&deg[dst[e]], 1);
}

__global__ void k_blocksum(const int* __restrict__ deg, int* __restrict__ bsum) {
  int i = blockIdx.x * 256 + threadIdx.x;
  int v = (i < N_NODES) ? deg[i] : 0;
  #pragma unroll
  for (int d = 32; d; d >>= 1) v += __shfl_down(v, d);
  __shared__ int wsum[4];
  if ((threadIdx.x & 63) == 0) wsum[threadIdx.x >> 6] = v;
  __syncthreads();
  if (threadIdx.x == 0) bsum[blockIdx.x] = wsum[0] + wsum[1] + wsum[2] + wsum[3];
}

// single-wave exclusive scan over block sums (nb ~ 391)
__global__ void k_scan_bsum(int* __restrict__ bsum, int nb, int* __restrict__ off) {
  int lane = threadIdx.x;
  int running = 0;
  for (int base = 0; base < nb; base += 64) {
    int i = base + lane;
    int v = (i < nb) ? bsum[i] : 0;
    int inc = v;
    #pragma unroll
    for (int d = 1; d < 64; d <<= 1) { int y = __shfl_up(inc, d); if (lane >= d) inc += y; }
    if (i < nb) bsum[i] = running + inc - v;
    running += __shfl(inc, 63);
  }
  if (lane == 0) off[N_NODES] = running;
}

__global__ void k_offsets(const int* __restrict__ deg, const int* __restrict__ bsum,
                          int* __restrict__ off, int* __restrict__ cur) {
  int i = blockIdx.x * 256 + threadIdx.x;
  int lane = threadIdx.x & 63, w = threadIdx.x >> 6;
  int v = (i < N_NODES) ? deg[i] : 0;
  int inc = v;
  #pragma unroll
  for (int d = 1; d < 64; d <<= 1) { int y = __shfl_up(inc, d); if (lane >= d) inc += y; }
  __shared__ int wtot[4];
  if (lane == 63) wtot[w] = inc;
  __syncthreads();
  int base = bsum[blockIdx.x];
  for (int j = 0; j < w; j++) base += wtot[j];
  if (i < N_NODES) {
    int ex = base + inc - v;
    off[i] = ex;
    cur[i] = ex;
  }
}

__global__ void k_fill(const int* __restrict__ src, const int* __restrict__ dst,
                       int* __restrict__ cur, int* __restrict__ esrc) {
  int stride = gridDim.x * blockDim.x;
  for (int e = blockIdx.x * blockDim.x + threadIdx.x; e < N_EDGES; e += stride) {
    int d = dst[e];
    int p = atomicAdd(&cur[d], 1);
    esrc[p] = src[e];
  }
}

// ---- fused SAGE layer: one wave per node, lane = output feature ------------

template <bool RELU>
__global__ void k_layer(const float* __restrict__ feat, const int* __restrict__ off,
                        const int* __restrict__ esrc,
                        const float* __restrict__ Ws, const float* __restrict__ Wn,
                        const float* __restrict__ bias, float* __restrict__ out) {
  const int lane = threadIdx.x & 63;
  const int wib  = threadIdx.x >> 6;
  const int wpb  = blockDim.x >> 6;
  const int wid  = blockIdx.x * wpb + wib;
  const int nw   = gridDim.x * wpb;

  // lane holds column `lane` of both weight matrices in VGPRs
  float wS[64], wN[64];
  #pragma unroll
  for (int k = 0; k < 64; k++) {
    wS[k] = Ws[k * 64 + lane];
    wN[k] = Wn[k * 64 + lane];
  }
  const float bv = bias[lane];

  for (int n = wid; n < N_NODES; n += nw) {
    const int o0 = off[n], o1 = off[n + 1];
    float acc = 0.f;
    int i = o0;
    for (; i + 4 <= o1; i += 4) {
      int s0 = esrc[i], s1 = esrc[i + 1], s2 = esrc[i + 2], s3 = esrc[i + 3];
      float a0 = feat[s0 * 64 + lane];
      float a1 = feat[s1 * 64 + lane];
      float a2 = feat[s2 * 64 + lane];
      float a3 = feat[s3 * 64 + lane];
      acc += (a0 + a1) + (a2 + a3);
    }
    for (; i < o1; ++i) acc += feat[esrc[i] * 64 + lane];
    const int dg = o1 - o0;
    acc = (dg > 0) ? acc * (1.0f / (float)dg) : 0.f;

    const float sv = feat[n * 64 + lane];
    float p0 = bv, p1 = 0.f, p2 = 0.f, p3 = 0.f;
    #pragma unroll
    for (int k = 0; k < 64; k += 2) {
      p0 += rlane(sv,  k)     * wS[k];
      p1 += rlane(acc, k)     * wN[k];
      p2 += rlane(sv,  k + 1) * wS[k + 1];
      p3 += rlane(acc, k + 1) * wN[k + 1];
    }
    float o = (p0 + p1) + (p2 + p3);
    if (RELU) o = fmaxf(o, 0.f);
    out[n * 64 + lane] = o;
  }
}

// ---- launch ----------------------------------------------------------------

extern "C" void kernel_launch(void* const* d_in, const int* in_sizes, int n_in,
                              void* d_out, int out_size, void* d_ws, size_t ws_size,
                              hipStream_t stream) {
  const float* x   = (const float*)d_in[0];
  const int*   src = (const int*)d_in[1];
  const int*   dst = (const int*)d_in[2];
  const float* Ws1 = (const float*)d_in[3];
  const float* Wn1 = (const float*)d_in[4];
  const float* b1  = (const float*)d_in[5];
  const float* Ws2 = (const float*)d_in[6];
  const float* Wn2 = (const float*)d_in[7];
  const float* b2  = (const float*)d_in[8];
  float* out = (float*)d_out;

  char* ws = (char*)d_ws;
  int*   deg  = (int*)(ws + 0);        // N ints
  int*   off  = (int*)(ws + 400128);   // N+1 ints
  int*   cur  = (int*)(ws + 800512);   // N ints
  int*   bsum = (int*)(ws + 1200640);  // ~400 ints
  int*   esrc = (int*)(ws + 1202688);  // E ints
  float* h    = (float*)(ws + 7602688);// N*64 f32  (ends ~33.2 MB)

  const int NB = (N_NODES + 255) / 256; // 391

  hipMemsetAsync(deg, 0, N_NODES * sizeof(int), stream);
  k_hist<<<2048, 256, 0, stream>>>(dst, deg);
  k_blocksum<<<NB, 256, 0, stream>>>(deg, bsum);
  k_scan_bsum<<<1, 64, 0, stream>>>(bsum, NB, off);
  k_offsets<<<NB, 256, 0, stream>>>(deg, bsum, off, cur);
  k_fill<<<2048, 256, 0, stream>>>(src, dst, cur, esrc);
  k_layer<true ><<<1024, 256, 0, stream>>>(x, off, esrc, Ws1, Wn1, b1, h);
  k_layer<false><<<1024, 256, 0, stream>>>(h, off, esrc, Ws2, Wn2, b2, out);
}